// Round 13
// baseline (773.348 us; speedup 1.0000x reference)
//
#include <hip/hip_runtime.h>
#include <stdint.h>

#define BB 32
#define LL 1024
#define CC 512
#define NN (BB * LL)      // 32768 positions
#define NLEVS 4
#define OUTD 11
#define LPAD 8            // zero pad rows per sequence (>= max dilation)
#define LROWS (LL + LPAD) // 1032 padded rows per sequence

typedef __attribute__((ext_vector_type(8))) short bf16x8;
typedef __attribute__((ext_vector_type(4))) float f32x4;

static __device__ __forceinline__ unsigned short f2bf(float f) {
    union { float f; uint32_t u; } v; v.f = f;
    uint32_t u = v.u;
    uint32_t r = (u + 0x7fffu + ((u >> 16) & 1u)) >> 16;  // RNE
    return (unsigned short)r;
}
static __device__ __forceinline__ float bf2f(unsigned short h) {
    union { uint32_t u; float f; } v; v.u = ((uint32_t)h) << 16;
    return v.f;
}

// async 16B global -> LDS (wave-uniform LDS base + lane*16)
static __device__ __forceinline__ void llds16(const unsigned short* g, unsigned short* l) {
    __builtin_amdgcn_global_load_lds(
        (const __attribute__((address_space(1))) unsigned int*)g,
        (__attribute__((address_space(3))) unsigned int*)l, 16, 0, 0);
}

// Fused prep: pack_w | embed | zero_pad | pack_dw, selected by block range.
// pack_w: thread = (cv, jj, co): reads 16 consecutive fp32 (8 ci x 2 taps,
// 4x float4, fully used) and writes BOTH tap regions (j=jj tap1, j=jj+64 tap0),
// 16B coalesced stores across co. 1024 blocks (was 16384 scalar blocks).
__global__ __launch_bounds__(256) void prep_kernel(
    const int* __restrict__ x, const float* __restrict__ emb,
    const float* __restrict__ w1, const float* __restrict__ w2,
    const float* __restrict__ dw,
    unsigned short* __restrict__ Hb0, unsigned short* __restrict__ Hb1,
    unsigned short* __restrict__ WpT, unsigned short* __restrict__ dwp)
{
    int b = blockIdx.x;
    if (b < 1024) {
        int t = b * 256 + threadIdx.x;             // < 262144
        int co = t & 511;
        int jj = (t >> 9) & 63;
        int cv = t >> 15;                           // 0..7
        int lvl = cv >> 1;
        const float* w = (cv & 1) ? w2 : w1;
        const float* src = w + ((size_t)(lvl * 512 + co) * 512 + jj * 8) * 2;
        float4 f0 = ((const float4*)src)[0];
        float4 f1 = ((const float4*)src)[1];
        float4 f2 = ((const float4*)src)[2];
        float4 f3 = ((const float4*)src)[3];
        ushort4 t1a = {f2bf(f0.y), f2bf(f0.w), f2bf(f1.y), f2bf(f1.w)};
        ushort4 t1b = {f2bf(f2.y), f2bf(f2.w), f2bf(f3.y), f2bf(f3.w)};
        ushort4 t0a = {f2bf(f0.x), f2bf(f0.z), f2bf(f1.x), f2bf(f1.z)};
        ushort4 t0b = {f2bf(f2.x), f2bf(f2.z), f2bf(f3.x), f2bf(f3.z)};
        unsigned short* d1 = WpT + ((size_t)(cv * 128 + jj) * 512 + co) * 8;
        unsigned short* d0 = WpT + ((size_t)(cv * 128 + jj + 64) * 512 + co) * 8;
        *(ushort4*)d1 = t1a; *(ushort4*)(d1 + 4) = t1b;
        *(ushort4*)d0 = t0a; *(ushort4*)(d0 + 4) = t0b;
    } else if (b < 9216) {
        int t = (b - 1024) * 256 + threadIdx.x;
        int n = t >> 6;
        int c8 = (t & 63) * 8;
        int idx = x[n];
        const float* src = emb + (size_t)idx * CC + c8;
        float4 v0 = *(const float4*)src;
        float4 v1 = *(const float4*)(src + 4);
        ushort4 a, bb;
        a.x = f2bf(v0.x); a.y = f2bf(v0.y); a.z = f2bf(v0.z); a.w = f2bf(v0.w);
        bb.x = f2bf(v1.x); bb.y = f2bf(v1.y); bb.z = f2bf(v1.z); bb.w = f2bf(v1.w);
        int prow = (n >> 10) * LROWS + LPAD + (n & (LL - 1));
        unsigned short* dst = Hb0 + (size_t)prow * CC + c8;
        *(ushort4*)dst = a;
        *(ushort4*)(dst + 4) = bb;
    } else if (b < 9344) {
        int t = (b - 9216) * 256 + threadIdx.x;    // 32768 uint4 stores
        unsigned short* base = (t >> 14) ? Hb1 : Hb0;
        int rem = t & 16383;
        int p = rem >> 9;
        int q = rem & 511;
        size_t off = (size_t)p * (LROWS * CC) + (size_t)q * 8;
        *(uint4*)(base + off) = (uint4){0u, 0u, 0u, 0u};
    } else {
        int e = (b - 9344) * 256 + threadIdx.x;    // 8192 halves
        int jb = e >> 7;
        int o = (e >> 3) & 15;
        int j = e & 7;
        dwp[e] = f2bf((o < OUTD) ? dw[o * CC + jb * 8 + j] : 0.f);
    }
}

// GEMM: out[n][co] = act( A-window . W + bias ), all activations bf16.
// R11 structure (best measured): 128n x 128co tile, shared-A, BK=64/buffer,
// 2 LDS slots, flag-based barrier-free K-loop, 4 blocks/CU.
// R13 refinement: ALL 16 B-frag loads hoisted to iteration top (before the
// done-spin and A-DMA issue). vmcnt retires in issue order, so the single
// vmcnt(4|5) after issue(it+1) drains A(it)+B(it) and leaves only A(it+1) in
// flight -> B latency overlaps the spin, compute phase is load-free.
// 16x16x32 MFMA 4x4/wave; 128-B-pitch XOR-swizzled LDS (zero-conflict).
// XCD swizzle: 4 co-blocks of an n-window land on one XCD.
// HAS_RES: v = relu(relu(acc+b) + res_bf16); in-place-safe (lane-owned elems).
#define BUFH (17 * 512)   // 136 rows x 64 halves = 17408 B per buffer
template <bool HAS_RES>
__global__ __launch_bounds__(256, 4) void conv_gemm(
    const unsigned short* __restrict__ Ain, const unsigned short* __restrict__ WpT,
    const float* __restrict__ bias, const unsigned short* __restrict__ resB,
    unsigned short* __restrict__ OutB, int d)
{
    __shared__ unsigned short sA[2 * BUFH];
    __shared__ int s_ready[8];
    __shared__ int s_done[8];

    const int tid = threadIdx.x;
    const int wave = tid >> 6, lane = tid & 63;

    const int bid = blockIdx.x;               // 0..1023
    const int xcd = bid & 7;
    const int local = bid >> 3;               // 0..127
    const int cb = local >> 5;                // 0..3
    const int nb = xcd + 8 * (local & 31);    // 0..255
    const int co0 = cb * 128;
    const int n0 = nb * 128;

    const int rbase = (n0 >> 10) * LROWS + LPAD + (n0 & (LL - 1));
    const int wm = (wave >> 1) * 64;           // wave n-stripe
    const int wn = (wave & 1) * 64;            // wave co-stripe
    const int lm = lane & 15, quad = lane >> 4;

    // staging lane decomposition: 8 rows x 8 chunks of 16B per llds16 (1 KB)
    const int r8 = lane >> 3;
    const int c8 = lane & 7;

    if (tid < 8) { s_ready[tid] = 0; s_done[tid] = 0; }
    __syncthreads();

    f32x4 acc[4][4];
#pragma unroll
    for (int i = 0; i < 4; ++i)
#pragma unroll
        for (int j = 0; j < 4; ++j) acc[i][j] = (f32x4){0.f, 0.f, 0.f, 0.f};

    // issue this wave's segments of ci-block `it` into slot it&1
    // wave0: segs 0,4,8,12,16 (5 loads); waves1-3: 4 loads
    auto issue = [&](int it) {
        const unsigned short* gA =
            Ain + (size_t)(rbase - 8 + r8) * CC + it * 64 + (c8 ^ r8) * 8;
        unsigned short* lbase = sA + (it & 1) * BUFH;
        for (int seg = wave; seg < 17; seg += 4)
            llds16(gA + (size_t)seg * 8 * CC, lbase + seg * 512);
    };
    auto spin4 = [&](int* p) {
        volatile int* vp = (volatile int*)p;
        while (*vp < 4) __builtin_amdgcn_s_sleep(1);
    };

    issue(0);

    for (int it = 0; it < 8; ++it) {
        // 1. ALL B frags of this it (issued before A(it+1); in flight during spin)
        bf16x8 ball[4][4];
#pragma unroll
        for (int s = 0; s < 4; ++s) {
            const int t = s >> 1, ks = s & 1;
            const int jb = t * 64 + it * 8 + ks * 4 + quad;
            const unsigned short* bbase = WpT + ((size_t)jb * 512 + co0 + wn + lm) * 8;
#pragma unroll
            for (int nt = 0; nt < 4; ++nt)
                ball[s][nt] = *(const bf16x8*)(bbase + (size_t)nt * 16 * 8);
        }

        // 2. stage next ci-block, then drain A(it)+B(it) only
        if (it < 7) {
            if (it >= 1) spin4(&s_done[it - 1]);     // slot (it+1)&1 free?
            issue(it + 1);
            if (wave == 0) __builtin_amdgcn_s_waitcnt(0xF75);  // vmcnt(5)
            else           __builtin_amdgcn_s_waitcnt(0xF74);  // vmcnt(4)
        } else {
            __builtin_amdgcn_s_waitcnt(0xF70);                 // vmcnt(0)
        }
        __asm__ volatile("" ::: "memory");
        if (lane == 0) atomicAdd(&s_ready[it], 1);
        spin4(&s_ready[it]);
        __asm__ volatile("" ::: "memory");

        const unsigned short* buf = sA + (it & 1) * BUFH;

        // step s = t*2 + ks: t = tap (0 current, 1 past), ks = K=32 slice
        auto loadA = [&](int s, bf16x8* af) {
            const int t = s >> 1, ks = s & 1;
            const int shift = t ? d : 0;
            const int rowoff = 8 - shift + wm;
            const int key = (8 - shift + lm) & 7;
            const int cpos = ((ks * 4 + quad) ^ key);
#pragma unroll
            for (int mt = 0; mt < 4; ++mt)
                af[mt] = *(const bf16x8*)&buf[(rowoff + mt * 16 + lm) * 64 + cpos * 8];
        };

        bf16x8 afc[4], afn[4];
        loadA(0, afc);
#pragma unroll
        for (int s = 0; s < 4; ++s) {
            if (s < 3) loadA(s + 1, afn);
#pragma unroll
            for (int mt = 0; mt < 4; ++mt)
#pragma unroll
                for (int nt = 0; nt < 4; ++nt)
                    acc[mt][nt] = __builtin_amdgcn_mfma_f32_16x16x32_bf16(
                        afc[mt], ball[s][nt], acc[mt][nt], 0, 0, 0);
            if (s < 3) {
#pragma unroll
                for (int q2 = 0; q2 < 4; ++q2) afc[q2] = afn[q2];
            }
        }

        __asm__ volatile("" ::: "memory");
        if (lane == 0) atomicAdd(&s_done[it], 1);
    }

    // epilogue: C/D layout col(co)=lane&15, row(n)=quad*4+reg
    float bv[4];
#pragma unroll
    for (int nt = 0; nt < 4; ++nt) bv[nt] = bias[co0 + wn + nt * 16 + lm];

#pragma unroll
    for (int mt = 0; mt < 4; ++mt) {
        int prow0 = rbase + wm + mt * 16 + quad * 4;
#pragma unroll
        for (int nt = 0; nt < 4; ++nt) {
            int co = co0 + wn + nt * 16 + lm;
#pragma unroll
            for (int r = 0; r < 4; ++r) {
                size_t off = (size_t)(prow0 + r) * CC + co;
                float v = acc[mt][nt][r] + bv[nt];
                v = fmaxf(v, 0.f);
                if (HAS_RES) {
                    v += bf2f(resB[off]);
                    v = fmaxf(v, 0.f);
                }
                OutB[off] = f2bf(v);
            }
        }
    }
}

// decode as per-wave MFMA mini-GEMM: B frags (decoder weights) hoisted into
// registers once per wave; each wave covers 32 rows (2 M-tiles) per block.
__global__ __launch_bounds__(256) void decode_kernel(
    const unsigned short* __restrict__ H, const unsigned short* __restrict__ dwp,
    const float* __restrict__ db, const int* __restrict__ mask,
    float* __restrict__ out)
{
    const int wave = threadIdx.x >> 6, lane = threadIdx.x & 63;
    const int lm = lane & 15, quad = lane >> 4;

    bf16x8 bfr[16];
#pragma unroll
    for (int ks = 0; ks < 16; ++ks)
        bfr[ks] = *(const bf16x8*)&dwp[((size_t)(ks * 4 + quad) * 16 + lm) * 8];

    const int base = blockIdx.x * 128 + wave * 32;   // 32-aligned: no seq crossing
#pragma unroll
    for (int sub = 0; sub < 2; ++sub) {
        int n0 = base + sub * 16;
        int prow = ((n0 + lm) >> 10) * LROWS + LPAD + ((n0 + lm) & (LL - 1));
        f32x4 acc = (f32x4){0.f, 0.f, 0.f, 0.f};
#pragma unroll
        for (int ks = 0; ks < 16; ++ks) {
            bf16x8 af = *(const bf16x8*)&H[(size_t)prow * CC + ks * 32 + quad * 8];
            acc = __builtin_amdgcn_mfma_f32_16x16x32_bf16(af, bfr[ks], acc, 0, 0, 0);
        }
        if (lm < OUTD) {
            float bo = db[lm];
#pragma unroll
            for (int r = 0; r < 4; ++r) {
                int n = n0 + quad * 4 + r;
                float v = (mask[n] != 0) ? (acc[r] + bo) : 0.f;
                out[(size_t)n * OUTD + lm] = v;
            }
        }
    }
}

extern "C" void kernel_launch(void* const* d_in, const int* in_sizes, int n_in,
                              void* d_out, int out_size, void* d_ws, size_t ws_size,
                              hipStream_t stream)
{
    const int* x = (const int*)d_in[0];
    const int* mask = (const int*)d_in[1];   // jnp bool_ staged as int32
    const float* emb = (const float*)d_in[2];
    const float* w1 = (const float*)d_in[3];
    const float* b1 = (const float*)d_in[4];
    const float* w2 = (const float*)d_in[5];
    const float* b2 = (const float*)d_in[6];
    const float* dw = (const float*)d_in[7];
    const float* db = (const float*)d_in[8];
    float* out = (float*)d_out;

    char* ws = (char*)d_ws;
    const size_t HBB = (size_t)BB * LROWS * CC * 2;       // 33.8 MB (padded bf16)
    unsigned short* Hb0 = (unsigned short*)ws;
    unsigned short* Hb1 = (unsigned short*)(ws + HBB);
    unsigned short* WpT = (unsigned short*)(ws + 2 * HBB); // k-major bf16 weights, 8 MB
    unsigned short* dwp = (unsigned short*)(ws + 2 * HBB + (size_t)NLEVS * 2 * CC * 1024 * 2);

    prep_kernel<<<9376, 256, 0, stream>>>(x, emb, w1, w2, dw, Hb0, Hb1, WpT, dwp);

    const int grid = (CC / 128) * (NN / 128);   // 4 * 256 = 1024 blocks = 4/CU
    for (int i = 0; i < NLEVS; ++i) {
        int d = 1 << i;
        const unsigned short* W1 = WpT + (size_t)(i * 2 + 0) * CC * 1024;
        const unsigned short* W2 = WpT + (size_t)(i * 2 + 1) * CC * 1024;
        // conv1: A=Hb0 -> Hb1
        conv_gemm<false><<<grid, 256, 0, stream>>>(Hb0, W1, b1 + i * CC, nullptr, Hb1, d);
        // conv2: A=Hb1, res=Hb0 (bf16), out=Hb0 (in place, lane-owned)
        conv_gemm<true><<<grid, 256, 0, stream>>>(Hb1, W2, b2 + i * CC, Hb0, Hb0, d);
    }
    decode_kernel<<<NN / 128, 256, 0, stream>>>(Hb0, dwp, db, mask, out);
}